// Round 2
// baseline (1796.014 us; speedup 1.0000x reference)
//
#include <hip/hip_runtime.h>
#include <hip/hip_bf16.h>
#include <math.h>

// Problem constants
#define B_      2
#define S_      2048
#define D_      2048
#define H_      16
#define NOPE_D  64
#define ROPE_DD 32
#define V_DD    64
#define QRANK   768
#define KVRANK  256
#define ROWS    (B_ * S_)   // 4096

// ---------------------------------------------------------------------------
// Generic fp32 GEMM: C[M,N] = A[M,K] @ B[K,N]
// Requirements: M % 64 == 0, N % 128 == 0, K % 16 == 0 (all our shapes obey).
// 256 threads, BM=64 BN=128 BK=16, each thread computes 4x8.
// ---------------------------------------------------------------------------
__global__ __launch_bounds__(256) void gemm_f32(const float* __restrict__ A,
                                                const float* __restrict__ Bm,
                                                float* __restrict__ C,
                                                int M, int N, int K) {
  __shared__ float As[64][17];    // padded: stride 17 words breaks pow2 conflicts
  __shared__ float Bs[16][132];   // stride 132 words = 528B (16B aligned)
  const int tid = threadIdx.x;
  const int m0 = blockIdx.y * 64;
  const int n0 = blockIdx.x * 128;
  const int tm = tid >> 4, tn = tid & 15;
  const int arow = tid >> 2, acol = (tid & 3) << 2;
  const int brow = tid >> 5, bcol = (tid & 31) << 2;

  float acc[4][8];
#pragma unroll
  for (int i = 0; i < 4; ++i)
#pragma unroll
    for (int j = 0; j < 8; ++j) acc[i][j] = 0.f;

  for (int k0 = 0; k0 < K; k0 += 16) {
    float4 av  = *(const float4*)&A [(size_t)(m0 + arow) * K + k0 + acol];
    float4 bv0 = *(const float4*)&Bm[(size_t)(k0 + brow) * N + n0 + bcol];
    float4 bv1 = *(const float4*)&Bm[(size_t)(k0 + brow + 8) * N + n0 + bcol];
    As[arow][acol + 0] = av.x;
    As[arow][acol + 1] = av.y;
    As[arow][acol + 2] = av.z;
    As[arow][acol + 3] = av.w;
    *(float4*)&Bs[brow][bcol]     = bv0;
    *(float4*)&Bs[brow + 8][bcol] = bv1;
    __syncthreads();
#pragma unroll
    for (int kk = 0; kk < 16; ++kk) {
      float a[4], bb[8];
#pragma unroll
      for (int i = 0; i < 4; ++i) a[i] = As[tm * 4 + i][kk];
      float4 b0 = *(float4*)&Bs[kk][tn * 8];
      float4 b1 = *(float4*)&Bs[kk][tn * 8 + 4];
      bb[0] = b0.x; bb[1] = b0.y; bb[2] = b0.z; bb[3] = b0.w;
      bb[4] = b1.x; bb[5] = b1.y; bb[6] = b1.z; bb[7] = b1.w;
#pragma unroll
      for (int i = 0; i < 4; ++i)
#pragma unroll
        for (int j = 0; j < 8; ++j) acc[i][j] = fmaf(a[i], bb[j], acc[i][j]);
    }
    __syncthreads();
  }
#pragma unroll
  for (int i = 0; i < 4; ++i) {
    size_t off = (size_t)(m0 + tm * 4 + i) * N + n0 + tn * 8;
    *(float4*)&C[off]     = make_float4(acc[i][0], acc[i][1], acc[i][2], acc[i][3]);
    *(float4*)&C[off + 4] = make_float4(acc[i][4], acc[i][5], acc[i][6], acc[i][7]);
  }
}

// ---------------------------------------------------------------------------
// In-place RMSNorm: x[row] *= rsqrt(mean(x^2) + eps) * g
// One block (256 thr) per row.
// ---------------------------------------------------------------------------
__global__ __launch_bounds__(256) void rmsnorm_inplace(float* __restrict__ x,
                                                       const float* __restrict__ g,
                                                       int cols, float inv_cols) {
  const int row = blockIdx.x;
  float* p = x + (size_t)row * cols;
  float ss = 0.f;
  for (int c = threadIdx.x; c < cols; c += 256) { float v = p[c]; ss += v * v; }
#pragma unroll
  for (int off = 32; off >= 1; off >>= 1) ss += __shfl_xor(ss, off, 64);
  __shared__ float wsum[4];
  if ((threadIdx.x & 63) == 0) wsum[threadIdx.x >> 6] = ss;
  __syncthreads();
  float tot = (wsum[0] + wsum[1]) + (wsum[2] + wsum[3]);
  float r = rsqrtf(tot * inv_cols + 1e-6f);
  for (int c = threadIdx.x; c < cols; c += 256) p[c] = p[c] * r * g[c];
}

// ---------------------------------------------------------------------------
// RoPE on q_rope [4096][H*32]. NOTE: reference's sin table == cos table!
// out_r = (xr - xi)*c ; out_i = (xr + xi)*c, c = cos(pos * theta^(-i/16)).
// One block per row; 256 threads = H_*16 pairs.
// ---------------------------------------------------------------------------
__global__ __launch_bounds__(256) void rope_q(float* __restrict__ qr) {
  const int row = blockIdx.x;
  const int t = threadIdx.x;
  const int h = t >> 4, i = t & 15;
  const int pos = row & (S_ - 1);
  float freq = powf(10000.0f, -(float)i / 16.0f);
  float c = cosf((float)pos * freq);
  float* p = qr + (size_t)row * (H_ * ROPE_DD) + h * ROPE_DD + 2 * i;
  float xr = p[0], xi = p[1];
  p[0] = (xr - xi) * c;
  p[1] = (xr + xi) * c;
}

// ---------------------------------------------------------------------------
// k_rope: kr[row][0:32] = rope( (x[row] @ w_k_rope) / H )
// One block per row.
// ---------------------------------------------------------------------------
__global__ __launch_bounds__(256) void krope_kernel(const float* __restrict__ x,
                                                    const float* __restrict__ w,
                                                    float* __restrict__ kr) {
  __shared__ float xs[2048];
  __shared__ float part[8][33];
  __shared__ float vals[32];
  const int row = blockIdx.x;
  const int t = threadIdx.x;
  const float* xp = x + (size_t)row * D_;
#pragma unroll
  for (int i = 0; i < 2; ++i) {
    int idx = t * 4 + i * 1024;
    *(float4*)&xs[idx] = *(const float4*)&xp[idx];
  }
  __syncthreads();
  const int c = t & 31, j = t >> 5;
  float s = 0.f;
  for (int k = j; k < D_; k += 8) s = fmaf(xs[k], w[k * 32 + c], s);
  part[j][c] = s;
  __syncthreads();
  if (t < 32) {
    float tot = 0.f;
#pragma unroll
    for (int jj = 0; jj < 8; ++jj) tot += part[jj][t];
    vals[t] = tot * (1.0f / (float)H_);
  }
  __syncthreads();
  if (t < 16) {
    const int pos = row & (S_ - 1);
    float freq = powf(10000.0f, -(float)t / 16.0f);
    float cc = cosf((float)pos * freq);
    float xr = vals[2 * t], xi = vals[2 * t + 1];
    kr[(size_t)row * 32 + 2 * t]     = (xr - xi) * cc;
    kr[(size_t)row * 32 + 2 * t + 1] = (xr + xi) * cc;
  }
}

// ---------------------------------------------------------------------------
// Flash attention, fp32. Tile: 32 q-rows x 32 k-cols. 256 threads.
// Thread (ty=tid/16, tx=tid%16): scores for rows {q0+ty, q0+ty+16} x cols
// {k0+tx, k0+tx+16}; accumulates out dims [tx*4, tx*4+4) for both rows.
// Row-wise reductions via shfl_xor within the 16 lanes sharing ty (same wave).
// ---------------------------------------------------------------------------
__global__ __launch_bounds__(256) void attn_f32(const float* __restrict__ qn,
                                                const float* __restrict__ qr,
                                                const float* __restrict__ kn,
                                                const float* __restrict__ kr,
                                                const float* __restrict__ vv,
                                                float* __restrict__ ao) {
  __shared__ float qs[32][108];  // d: 0..63 nope, 64..95 rope. stride 432B (16B-aligned)
  __shared__ float ks[32][108];
  __shared__ float vs[32][68];
  __shared__ float ps[32][36];
  const int q0 = blockIdx.x * 32;
  const int bh = blockIdx.y;
  const int b = bh >> 4, h = bh & 15;
  const int tid = threadIdx.x;
  const int ty = tid >> 4, tx = tid & 15;
  const size_t rowbase = (size_t)b * S_;
  const float scale = 0.10206207261596575f;  // 1/sqrt(96)

  {  // load Q tile (scaled)
    const int lf = tid & 15, lr = tid >> 4;
#pragma unroll
    for (int p = 0; p < 2; ++p) {
      int row = lr + p * 16;
      float4 v = *(const float4*)&qn[((rowbase + q0 + row) << 10) + (h << 6) + (lf << 2)];
      v.x *= scale; v.y *= scale; v.z *= scale; v.w *= scale;
      *(float4*)&qs[row][lf << 2] = v;
    }
    const int rf = tid & 7, rr = tid >> 3;
    float4 v = *(const float4*)&qr[((rowbase + q0 + rr) << 9) + (h << 5) + (rf << 2)];
    v.x *= scale; v.y *= scale; v.z *= scale; v.w *= scale;
    *(float4*)&qs[rr][64 + (rf << 2)] = v;
  }

  float m_a = -1e30f, m_b = -1e30f, l_a = 0.f, l_b = 0.f;
  float acc0[4] = {0, 0, 0, 0}, acc1[4] = {0, 0, 0, 0};

  for (int k0 = 0; k0 <= q0; k0 += 32) {
    __syncthreads();  // prev iter's ks/vs reads done; q-tile visible on first iter
    {  // load K,V tiles
      const int lf = tid & 15, lr = tid >> 4;
#pragma unroll
      for (int p = 0; p < 2; ++p) {
        int row = lr + p * 16;
        *(float4*)&ks[row][lf << 2] =
            *(const float4*)&kn[((rowbase + k0 + row) << 10) + (h << 6) + (lf << 2)];
        *(float4*)&vs[row][lf << 2] =
            *(const float4*)&vv[((rowbase + k0 + row) << 10) + (h << 6) + (lf << 2)];
      }
      const int rf = tid & 7, rr = tid >> 3;
      *(float4*)&ks[rr][64 + (rf << 2)] =
          *(const float4*)&kr[((rowbase + k0 + rr) << 5) + (rf << 2)];
    }
    __syncthreads();

    float s00 = 0, s01 = 0, s10 = 0, s11 = 0;
#pragma unroll
    for (int d = 0; d < 24; ++d) {
      float4 qa = *(float4*)&qs[ty][d << 2];
      float4 qb = *(float4*)&qs[ty + 16][d << 2];
      float4 ka = *(float4*)&ks[tx][d << 2];
      float4 kb = *(float4*)&ks[tx + 16][d << 2];
      s00 += qa.x * ka.x + qa.y * ka.y + qa.z * ka.z + qa.w * ka.w;
      s01 += qa.x * kb.x + qa.y * kb.y + qa.z * kb.z + qa.w * kb.w;
      s10 += qb.x * ka.x + qb.y * ka.y + qb.z * ka.z + qb.w * ka.w;
      s11 += qb.x * kb.x + qb.y * kb.y + qb.z * kb.z + qb.w * kb.w;
    }
    if (k0 == q0) {  // diagonal tile: mask k > q
      if (tx > ty)      { s00 = -1e30f; s11 = -1e30f; }
      if (tx + 16 > ty) { s01 = -1e30f; }
      // s10: col tx (<=15) vs row ty+16 (>=16) -> never masked
    }
    float tm_a = fmaxf(s00, s01), tm_b = fmaxf(s10, s11);
#pragma unroll
    for (int off = 8; off >= 1; off >>= 1) {
      tm_a = fmaxf(tm_a, __shfl_xor(tm_a, off, 64));
      tm_b = fmaxf(tm_b, __shfl_xor(tm_b, off, 64));
    }
    float mna = fmaxf(m_a, tm_a), mnb = fmaxf(m_b, tm_b);
    float ra = expf(m_a - mna), rb = expf(m_b - mnb);
    float p00 = expf(s00 - mna), p01 = expf(s01 - mna);
    float p10 = expf(s10 - mnb), p11 = expf(s11 - mnb);
    float tsa = p00 + p01, tsb = p10 + p11;
#pragma unroll
    for (int off = 8; off >= 1; off >>= 1) {
      tsa += __shfl_xor(tsa, off, 64);
      tsb += __shfl_xor(tsb, off, 64);
    }
    l_a = l_a * ra + tsa;
    l_b = l_b * rb + tsb;
    m_a = mna; m_b = mnb;
#pragma unroll
    for (int j = 0; j < 4; ++j) { acc0[j] *= ra; acc1[j] *= rb; }
    // share p within each q-row's 16-lane group (same wave -> no __syncthreads
    // needed; wave_barrier stops the compiler hoisting the reads above writes)
    ps[ty][tx] = p00;      ps[ty][tx + 16] = p01;
    ps[ty + 16][tx] = p10; ps[ty + 16][tx + 16] = p11;
    __builtin_amdgcn_wave_barrier();
#pragma unroll
    for (int k = 0; k < 32; ++k) {
      float4 v = *(float4*)&vs[k][tx << 2];
      float pa = ps[ty][k], pb = ps[ty + 16][k];
      acc0[0] = fmaf(pa, v.x, acc0[0]); acc0[1] = fmaf(pa, v.y, acc0[1]);
      acc0[2] = fmaf(pa, v.z, acc0[2]); acc0[3] = fmaf(pa, v.w, acc0[3]);
      acc1[0] = fmaf(pb, v.x, acc1[0]); acc1[1] = fmaf(pb, v.y, acc1[1]);
      acc1[2] = fmaf(pb, v.z, acc1[2]); acc1[3] = fmaf(pb, v.w, acc1[3]);
    }
    __builtin_amdgcn_wave_barrier();
  }
  const float iva = 1.f / l_a, ivb = 1.f / l_b;
  size_t oa = ((rowbase + q0 + ty) << 10) + (h << 6) + (tx << 2);
  size_t ob = ((rowbase + q0 + ty + 16) << 10) + (h << 6) + (tx << 2);
  *(float4*)&ao[oa] = make_float4(acc0[0] * iva, acc0[1] * iva, acc0[2] * iva, acc0[3] * iva);
  *(float4*)&ao[ob] = make_float4(acc1[0] * ivb, acc1[1] * ivb, acc1[2] * ivb, acc1[3] * ivb);
}

// ---------------------------------------------------------------------------
extern "C" void kernel_launch(void* const* d_in, const int* in_sizes, int n_in,
                              void* d_out, int out_size, void* d_ws, size_t ws_size,
                              hipStream_t stream) {
  const float* x        = (const float*)d_in[0];
  const float* w_cq     = (const float*)d_in[1];
  const float* w_q_nope = (const float*)d_in[2];
  const float* w_q_rope = (const float*)d_in[3];
  const float* q_g      = (const float*)d_in[4];
  const float* w_ckv    = (const float*)d_in[5];
  const float* w_k_nope = (const float*)d_in[6];
  const float* w_v      = (const float*)d_in[7];
  const float* kv_g     = (const float*)d_in[8];
  const float* w_k_rope = (const float*)d_in[9];
  const float* w_proj   = (const float*)d_in[10];
  float* out = (float*)d_out;

  // workspace layout (floats): total ~23.2M floats = ~92.8 MB
  float* ws = (float*)d_ws;
  float* cq  = ws;                 // [4096][768]
  float* ckv = cq  + (size_t)ROWS * QRANK;          // [4096][256]
  float* qn  = ckv + (size_t)ROWS * KVRANK;         // [4096][1024]
  float* qr  = qn  + (size_t)ROWS * H_ * NOPE_D;    // [4096][512]
  float* kn  = qr  + (size_t)ROWS * H_ * ROPE_DD;   // [4096][1024]
  float* vv  = kn  + (size_t)ROWS * H_ * NOPE_D;    // [4096][1024]
  float* kr  = vv  + (size_t)ROWS * H_ * V_DD;      // [4096][32]
  float* ao  = kr  + (size_t)ROWS * ROPE_DD;        // [4096][1024]

  // 1. cq = x @ w_cq   [4096,768,2048]
  gemm_f32<<<dim3(QRANK / 128, ROWS / 64), 256, 0, stream>>>(x, w_cq, cq, ROWS, QRANK, D_);
  // 2. rmsnorm(cq) * q_g
  rmsnorm_inplace<<<ROWS, 256, 0, stream>>>(cq, q_g, QRANK, 1.0f / QRANK);
  // 3. qn = cq @ w_q_nope  [4096,1024,768]
  gemm_f32<<<dim3(H_ * NOPE_D / 128, ROWS / 64), 256, 0, stream>>>(cq, w_q_nope, qn, ROWS, H_ * NOPE_D, QRANK);
  // 4. qr = cq @ w_q_rope  [4096,512,768]
  gemm_f32<<<dim3(H_ * ROPE_DD / 128, ROWS / 64), 256, 0, stream>>>(cq, w_q_rope, qr, ROWS, H_ * ROPE_DD, QRANK);
  // 5. rope(qr)
  rope_q<<<ROWS, 256, 0, stream>>>(qr);
  // 6. ckv = x @ w_ckv  [4096,256,2048]
  gemm_f32<<<dim3(KVRANK / 128, ROWS / 64), 256, 0, stream>>>(x, w_ckv, ckv, ROWS, KVRANK, D_);
  // 7. rmsnorm(ckv) * kv_g
  rmsnorm_inplace<<<ROWS, 256, 0, stream>>>(ckv, kv_g, KVRANK, 1.0f / KVRANK);
  // 8. kn = ckv @ w_k_nope  [4096,1024,256]
  gemm_f32<<<dim3(H_ * NOPE_D / 128, ROWS / 64), 256, 0, stream>>>(ckv, w_k_nope, kn, ROWS, H_ * NOPE_D, KVRANK);
  // 9. vv = ckv @ w_v  [4096,1024,256]
  gemm_f32<<<dim3(H_ * V_DD / 128, ROWS / 64), 256, 0, stream>>>(ckv, w_v, vv, ROWS, H_ * V_DD, KVRANK);
  // 10. kr = rope((x @ w_k_rope)/H)
  krope_kernel<<<ROWS, 256, 0, stream>>>(x, w_k_rope, kr);
  // 11. attention -> ao [4096][1024] (layout == (b,s,h*64+d))
  attn_f32<<<dim3(S_ / 32, B_ * H_), 256, 0, stream>>>(qn, qr, kn, kr, vv, ao);
  // 12. out = ao @ w_proj  [4096,2048,1024]
  gemm_f32<<<dim3(D_ / 128, ROWS / 64), 256, 0, stream>>>(ao, w_proj, out, ROWS, D_, H_ * V_DD);
}

// Round 3
// 790.419 us; speedup vs baseline: 2.2722x; 2.2722x over previous
//
#include <hip/hip_runtime.h>
#include <hip/hip_bf16.h>
#include <math.h>

#define B_      2
#define S_      2048
#define D_      2048
#define H_      16
#define NOPE_D  64
#define ROPE_DD 32
#define V_DD    64
#define QRANK   768
#define KVRANK  256
#define ROWS    (B_ * S_)   // 4096

typedef __attribute__((ext_vector_type(8))) short short8;
typedef __attribute__((ext_vector_type(4))) float f32x4;
typedef __attribute__((ext_vector_type(4))) unsigned short ushort4v;

__device__ __forceinline__ float bf2f(unsigned short u) {
  return __uint_as_float(((unsigned)u) << 16);
}
__device__ __forceinline__ unsigned short f2bf(float f) {  // RNE
  unsigned u = __float_as_uint(f);
  return (unsigned short)((u + 0x7fffu + ((u >> 16) & 1u)) >> 16);
}

// ---------------------------------------------------------------------------
// cast fp32 -> bf16, 8 elems/thread
// ---------------------------------------------------------------------------
__global__ __launch_bounds__(256) void cast_to_bf16(const float* __restrict__ in,
                                                    unsigned short* __restrict__ out,
                                                    int n) {
  int i = (blockIdx.x * 256 + threadIdx.x) * 8;
  if (i >= n) return;
  float4 a = *(const float4*)(in + i);
  float4 b = *(const float4*)(in + i + 4);
  unsigned short r[8] = {f2bf(a.x), f2bf(a.y), f2bf(a.z), f2bf(a.w),
                         f2bf(b.x), f2bf(b.y), f2bf(b.z), f2bf(b.w)};
  *(ushort4v*)(out + i)     = *(ushort4v*)&r[0];
  *(ushort4v*)(out + i + 4) = *(ushort4v*)&r[4];
}

// ---------------------------------------------------------------------------
// transpose + cast: in [R][C] fp32 -> out [C][R] bf16.  R,C % 32 == 0.
// ---------------------------------------------------------------------------
__global__ __launch_bounds__(256) void transpose_cast(const float* __restrict__ in,
                                                      unsigned short* __restrict__ out,
                                                      int R, int C) {
  __shared__ unsigned short t[32][33];
  const int c0 = blockIdx.x * 32, r0 = blockIdx.y * 32;
  const int tx = threadIdx.x & 31, ty = threadIdx.x >> 5;  // ty 0..7
#pragma unroll
  for (int i = 0; i < 32; i += 8)
    t[ty + i][tx] = f2bf(in[(size_t)(r0 + ty + i) * C + c0 + tx]);
  __syncthreads();
#pragma unroll
  for (int i = 0; i < 32; i += 8)
    out[(size_t)(c0 + ty + i) * R + r0 + tx] = t[tx][ty + i];
}

// ---------------------------------------------------------------------------
// bf16 MFMA GEMM (TN): A [M][K] bf16, Bt [N][K] bf16, C [M][N] (f32 or bf16).
// M%128==0, N%128==0, K%32==0. 256 thr = 4 waves, tile 128x128, BK=32.
// LDS granule XOR-swizzle (g ^= row&3) keeps ds_read_b128 conflict-free.
// MFMA 16x16x32_bf16: A frag lane l -> row l&15, k=(l>>4)*8+j.
// C/D: col = lane&15, row = (lane>>4)*4 + reg   [m89-verified layout].
// ---------------------------------------------------------------------------
__global__ __launch_bounds__(256) void gemm_bf16(const unsigned short* __restrict__ A,
                                                 const unsigned short* __restrict__ Bt,
                                                 void* __restrict__ Cv,
                                                 int M, int N, int K, int c_bf16) {
  __shared__ unsigned short As[128 * 32];
  __shared__ unsigned short Bs[128 * 32];
  const int tid = threadIdx.x;
  const int lane = tid & 63;
  const int wave = tid >> 6;
  const int wm = (wave >> 1) << 6;  // 0 / 64
  const int wn = (wave & 1) << 6;
  const int m0 = blockIdx.y * 128, n0 = blockIdx.x * 128;

  // staging: thread t -> row t>>1, granules {2*(t&1), 2*(t&1)+1} (8 bf16 each)
  const int srow = tid >> 1;
  const int sg = (tid & 1) * 2;
  const size_t a_base = (size_t)(m0 + srow) * K + sg * 8;
  const size_t b_base = (size_t)(n0 + srow) * K + sg * 8;
  const int w0 = srow * 64 + ((sg ^ (srow & 3)) << 4);
  const int w1 = srow * 64 + (((sg + 1) ^ (srow & 3)) << 4);

  // fragment read byte-offsets
  const int frow = lane & 15, fg = lane >> 4;
  int a_roff[4], b_roff[4];
#pragma unroll
  for (int m = 0; m < 4; ++m) {
    int r = wm + m * 16 + frow;
    a_roff[m] = r * 64 + ((fg ^ (r & 3)) << 4);
  }
#pragma unroll
  for (int n = 0; n < 4; ++n) {
    int r = wn + n * 16 + frow;
    b_roff[n] = r * 64 + ((fg ^ (r & 3)) << 4);
  }

  f32x4 acc[4][4];
#pragma unroll
  for (int m = 0; m < 4; ++m)
#pragma unroll
    for (int n = 0; n < 4; ++n) acc[m][n] = (f32x4){0.f, 0.f, 0.f, 0.f};

  for (int k0 = 0; k0 < K; k0 += 32) {
    uint4 va  = *(const uint4*)(A + a_base + k0);
    uint4 va2 = *(const uint4*)(A + a_base + k0 + 8);
    uint4 vb  = *(const uint4*)(Bt + b_base + k0);
    uint4 vb2 = *(const uint4*)(Bt + b_base + k0 + 8);
    __syncthreads();  // previous iteration's LDS reads complete
    *(uint4*)((char*)As + w0) = va;
    *(uint4*)((char*)As + w1) = va2;
    *(uint4*)((char*)Bs + w0) = vb;
    *(uint4*)((char*)Bs + w1) = vb2;
    __syncthreads();
    short8 af[4], bfr[4];
#pragma unroll
    for (int m = 0; m < 4; ++m) af[m] = *(const short8*)((const char*)As + a_roff[m]);
#pragma unroll
    for (int n = 0; n < 4; ++n) bfr[n] = *(const short8*)((const char*)Bs + b_roff[n]);
#pragma unroll
    for (int m = 0; m < 4; ++m)
#pragma unroll
      for (int n = 0; n < 4; ++n)
        acc[m][n] = __builtin_amdgcn_mfma_f32_16x16x32_bf16(af[m], bfr[n], acc[m][n], 0, 0, 0);
  }

  const int crow = (lane >> 4) * 4;
  const int ccol = lane & 15;
  if (c_bf16) {
    unsigned short* Cb = (unsigned short*)Cv;
#pragma unroll
    for (int m = 0; m < 4; ++m)
#pragma unroll
      for (int n = 0; n < 4; ++n)
#pragma unroll
        for (int r = 0; r < 4; ++r)
          Cb[(size_t)(m0 + wm + m * 16 + crow + r) * N + n0 + wn + n * 16 + ccol] =
              f2bf(acc[m][n][r]);
  } else {
    float* Cf = (float*)Cv;
#pragma unroll
    for (int m = 0; m < 4; ++m)
#pragma unroll
      for (int n = 0; n < 4; ++n)
#pragma unroll
        for (int r = 0; r < 4; ++r)
          Cf[(size_t)(m0 + wm + m * 16 + crow + r) * N + n0 + wn + n * 16 + ccol] =
              acc[m][n][r];
  }
}

// ---------------------------------------------------------------------------
// In-place RMSNorm on bf16 buffer: x *= rsqrt(mean(x^2)+eps) * g
// ---------------------------------------------------------------------------
__global__ __launch_bounds__(256) void rmsnorm_bf16(unsigned short* __restrict__ x,
                                                    const float* __restrict__ g,
                                                    int cols, float inv_cols) {
  const int row = blockIdx.x;
  unsigned short* p = x + (size_t)row * cols;
  float ss = 0.f;
  for (int c = threadIdx.x; c < cols; c += 256) { float v = bf2f(p[c]); ss += v * v; }
#pragma unroll
  for (int off = 32; off >= 1; off >>= 1) ss += __shfl_xor(ss, off, 64);
  __shared__ float wsum[4];
  if ((threadIdx.x & 63) == 0) wsum[threadIdx.x >> 6] = ss;
  __syncthreads();
  float tot = (wsum[0] + wsum[1]) + (wsum[2] + wsum[3]);
  float r = rsqrtf(tot * inv_cols + 1e-6f);
  for (int c = threadIdx.x; c < cols; c += 256) p[c] = f2bf(bf2f(p[c]) * r * g[c]);
}

// ---------------------------------------------------------------------------
// RoPE on q_rope [4096][H*32] fp32. sin table == cos table in the reference.
// ---------------------------------------------------------------------------
__global__ __launch_bounds__(256) void rope_q(float* __restrict__ qr) {
  const int row = blockIdx.x;
  const int t = threadIdx.x;
  const int h = t >> 4, i = t & 15;
  const int pos = row & (S_ - 1);
  float freq = powf(10000.0f, -(float)i / 16.0f);
  float c = cosf((float)pos * freq);
  float* p = qr + (size_t)row * (H_ * ROPE_DD) + h * ROPE_DD + 2 * i;
  float xr = p[0], xi = p[1];
  p[0] = (xr - xi) * c;
  p[1] = (xr + xi) * c;
}

// ---------------------------------------------------------------------------
// k_rope: kr[row][0:32] = rope( (x[row] @ w_k_rope) / H )   (fp32 path)
// ---------------------------------------------------------------------------
__global__ __launch_bounds__(256) void krope_kernel(const float* __restrict__ x,
                                                    const float* __restrict__ w,
                                                    float* __restrict__ kr) {
  __shared__ float xs[2048];
  __shared__ float part[8][33];
  __shared__ float vals[32];
  const int row = blockIdx.x;
  const int t = threadIdx.x;
  const float* xp = x + (size_t)row * D_;
#pragma unroll
  for (int i = 0; i < 2; ++i) {
    int idx = t * 4 + i * 1024;
    *(float4*)&xs[idx] = *(const float4*)&xp[idx];
  }
  __syncthreads();
  const int c = t & 31, j = t >> 5;
  float s = 0.f;
  for (int k = j; k < D_; k += 8) s = fmaf(xs[k], w[k * 32 + c], s);
  part[j][c] = s;
  __syncthreads();
  if (t < 32) {
    float tot = 0.f;
#pragma unroll
    for (int jj = 0; jj < 8; ++jj) tot += part[jj][t];
    vals[t] = tot * (1.0f / (float)H_);
  }
  __syncthreads();
  if (t < 16) {
    const int pos = row & (S_ - 1);
    float freq = powf(10000.0f, -(float)t / 16.0f);
    float cc = cosf((float)pos * freq);
    float xr = vals[2 * t], xi = vals[2 * t + 1];
    kr[(size_t)row * 32 + 2 * t]     = (xr - xi) * cc;
    kr[(size_t)row * 32 + 2 * t + 1] = (xr + xi) * cc;
  }
}

// ---------------------------------------------------------------------------
// Flash attention fp32, diagonally paired for causal load balance:
// block pair p handles q-tiles {p, 63-p} -> uniform 65 tile-iters per block.
// Thread (ty,tx): rows {q0+ty, q0+ty+16} x cols {k0+tx, k0+tx+16}.
// Output written as bf16 [4096][1024].
// ---------------------------------------------------------------------------
__global__ __launch_bounds__(256) void attn_f32(const float* __restrict__ qn,
                                                const float* __restrict__ qr,
                                                const float* __restrict__ kn,
                                                const float* __restrict__ kr,
                                                const float* __restrict__ vv,
                                                unsigned short* __restrict__ ao) {
  __shared__ float qs[32][108];
  __shared__ float ks[32][108];
  __shared__ float vs[32][68];
  __shared__ float ps[32][36];
  const int pair = blockIdx.x;
  const int bh = blockIdx.y;
  const int b = bh >> 4, h = bh & 15;
  const int tid = threadIdx.x;
  const int ty = tid >> 4, tx = tid & 15;
  const size_t rowbase = (size_t)b * S_;
  const float scale = 0.10206207261596575f;  // 1/sqrt(96)

  for (int half = 0; half < 2; ++half) {
    const int q0 = (half ? (63 - pair) : pair) * 32;
    __syncthreads();  // prior half's compute (reads of qs) fully done
    {  // load Q tile (scaled)
      const int lf = tid & 15, lr = tid >> 4;
#pragma unroll
      for (int p = 0; p < 2; ++p) {
        int row = lr + p * 16;
        float4 v = *(const float4*)&qn[((rowbase + q0 + row) << 10) + (h << 6) + (lf << 2)];
        v.x *= scale; v.y *= scale; v.z *= scale; v.w *= scale;
        *(float4*)&qs[row][lf << 2] = v;
      }
      const int rf = tid & 7, rr = tid >> 3;
      float4 v = *(const float4*)&qr[((rowbase + q0 + rr) << 9) + (h << 5) + (rf << 2)];
      v.x *= scale; v.y *= scale; v.z *= scale; v.w *= scale;
      *(float4*)&qs[rr][64 + (rf << 2)] = v;
    }

    float m_a = -1e30f, m_b = -1e30f, l_a = 0.f, l_b = 0.f;
    float acc0[4] = {0, 0, 0, 0}, acc1[4] = {0, 0, 0, 0};

    for (int k0 = 0; k0 <= q0; k0 += 32) {
      __syncthreads();
      {  // load K,V tiles
        const int lf = tid & 15, lr = tid >> 4;
#pragma unroll
        for (int p = 0; p < 2; ++p) {
          int row = lr + p * 16;
          *(float4*)&ks[row][lf << 2] =
              *(const float4*)&kn[((rowbase + k0 + row) << 10) + (h << 6) + (lf << 2)];
          *(float4*)&vs[row][lf << 2] =
              *(const float4*)&vv[((rowbase + k0 + row) << 10) + (h << 6) + (lf << 2)];
        }
        const int rf = tid & 7, rr = tid >> 3;
        *(float4*)&ks[rr][64 + (rf << 2)] =
            *(const float4*)&kr[((rowbase + k0 + rr) << 5) + (rf << 2)];
      }
      __syncthreads();

      float s00 = 0, s01 = 0, s10 = 0, s11 = 0;
#pragma unroll
      for (int d = 0; d < 24; ++d) {
        float4 qa = *(float4*)&qs[ty][d << 2];
        float4 qb = *(float4*)&qs[ty + 16][d << 2];
        float4 ka = *(float4*)&ks[tx][d << 2];
        float4 kb = *(float4*)&ks[tx + 16][d << 2];
        s00 = fmaf(qa.x, ka.x, s00); s00 = fmaf(qa.y, ka.y, s00);
        s00 = fmaf(qa.z, ka.z, s00); s00 = fmaf(qa.w, ka.w, s00);
        s01 = fmaf(qa.x, kb.x, s01); s01 = fmaf(qa.y, kb.y, s01);
        s01 = fmaf(qa.z, kb.z, s01); s01 = fmaf(qa.w, kb.w, s01);
        s10 = fmaf(qb.x, ka.x, s10); s10 = fmaf(qb.y, ka.y, s10);
        s10 = fmaf(qb.z, ka.z, s10); s10 = fmaf(qb.w, ka.w, s10);
        s11 = fmaf(qb.x, kb.x, s11); s11 = fmaf(qb.y, kb.y, s11);
        s11 = fmaf(qb.z, kb.z, s11); s11 = fmaf(qb.w, kb.w, s11);
      }
      if (k0 == q0) {  // diagonal: mask k > q
        if (tx > ty)      { s00 = -1e30f; s11 = -1e30f; }
        if (tx + 16 > ty) { s01 = -1e30f; }
      }
      float tm_a = fmaxf(s00, s01), tm_b = fmaxf(s10, s11);
#pragma unroll
      for (int off = 8; off >= 1; off >>= 1) {
        tm_a = fmaxf(tm_a, __shfl_xor(tm_a, off, 64));
        tm_b = fmaxf(tm_b, __shfl_xor(tm_b, off, 64));
      }
      float mna = fmaxf(m_a, tm_a), mnb = fmaxf(m_b, tm_b);
      float ra = expf(m_a - mna), rb = expf(m_b - mnb);
      float p00 = expf(s00 - mna), p01 = expf(s01 - mna);
      float p10 = expf(s10 - mnb), p11 = expf(s11 - mnb);
      float tsa = p00 + p01, tsb = p10 + p11;
#pragma unroll
      for (int off = 8; off >= 1; off >>= 1) {
        tsa += __shfl_xor(tsa, off, 64);
        tsb += __shfl_xor(tsb, off, 64);
      }
      l_a = l_a * ra + tsa;
      l_b = l_b * rb + tsb;
      m_a = mna; m_b = mnb;
#pragma unroll
      for (int j = 0; j < 4; ++j) { acc0[j] *= ra; acc1[j] *= rb; }
      ps[ty][tx] = p00;      ps[ty][tx + 16] = p01;
      ps[ty + 16][tx] = p10; ps[ty + 16][tx + 16] = p11;
      __builtin_amdgcn_wave_barrier();
#pragma unroll
      for (int k = 0; k < 32; ++k) {
        float4 v = *(float4*)&vs[k][tx << 2];
        float pa = ps[ty][k], pb = ps[ty + 16][k];
        acc0[0] = fmaf(pa, v.x, acc0[0]); acc0[1] = fmaf(pa, v.y, acc0[1]);
        acc0[2] = fmaf(pa, v.z, acc0[2]); acc0[3] = fmaf(pa, v.w, acc0[3]);
        acc1[0] = fmaf(pb, v.x, acc1[0]); acc1[1] = fmaf(pb, v.y, acc1[1]);
        acc1[2] = fmaf(pb, v.z, acc1[2]); acc1[3] = fmaf(pb, v.w, acc1[3]);
      }
      __builtin_amdgcn_wave_barrier();
    }
    const float iva = 1.f / l_a, ivb = 1.f / l_b;
    size_t oa = ((rowbase + q0 + ty) << 10) + (h << 6) + (tx << 2);
    size_t ob = ((rowbase + q0 + ty + 16) << 10) + (h << 6) + (tx << 2);
    ushort4v o0 = {f2bf(acc0[0] * iva), f2bf(acc0[1] * iva), f2bf(acc0[2] * iva), f2bf(acc0[3] * iva)};
    ushort4v o1 = {f2bf(acc1[0] * ivb), f2bf(acc1[1] * ivb), f2bf(acc1[2] * ivb), f2bf(acc1[3] * ivb)};
    *(ushort4v*)&ao[oa] = o0;
    *(ushort4v*)&ao[ob] = o1;
  }
}

// ---------------------------------------------------------------------------
extern "C" void kernel_launch(void* const* d_in, const int* in_sizes, int n_in,
                              void* d_out, int out_size, void* d_ws, size_t ws_size,
                              hipStream_t stream) {
  const float* x        = (const float*)d_in[0];
  const float* w_cq     = (const float*)d_in[1];
  const float* w_q_nope = (const float*)d_in[2];
  const float* w_q_rope = (const float*)d_in[3];
  const float* q_g      = (const float*)d_in[4];
  const float* w_ckv    = (const float*)d_in[5];
  const float* w_k_nope = (const float*)d_in[6];
  const float* w_v      = (const float*)d_in[7];
  const float* kv_g     = (const float*)d_in[8];
  const float* w_k_rope = (const float*)d_in[9];
  const float* w_proj   = (const float*)d_in[10];
  float* out = (float*)d_out;

  // ---- workspace layout ----
  char* w = (char*)d_ws;
  float* qn = (float*)w;                 w += (size_t)ROWS * 1024 * 4;   // f32
  float* qr = (float*)w;                 w += (size_t)ROWS * 512 * 4;
  float* kn = (float*)w;                 w += (size_t)ROWS * 1024 * 4;
  float* vv = (float*)w;                 w += (size_t)ROWS * 1024 * 4;
  float* kr = (float*)w;                 w += (size_t)ROWS * 32 * 4;
  unsigned short* xb    = (unsigned short*)w; w += (size_t)ROWS * 2048 * 2;
  unsigned short* cqb   = (unsigned short*)w; w += (size_t)ROWS * QRANK * 2;
  unsigned short* ckvb  = (unsigned short*)w; w += (size_t)ROWS * KVRANK * 2;
  unsigned short* aob   = (unsigned short*)w; w += (size_t)ROWS * 1024 * 2;
  unsigned short* wcqT  = (unsigned short*)w; w += (size_t)QRANK * 2048 * 2;
  unsigned short* wqnT  = (unsigned short*)w; w += (size_t)1024 * QRANK * 2;
  unsigned short* wqrT  = (unsigned short*)w; w += (size_t)512 * QRANK * 2;
  unsigned short* wckvT = (unsigned short*)w; w += (size_t)KVRANK * 2048 * 2;
  unsigned short* wknT  = (unsigned short*)w; w += (size_t)1024 * KVRANK * 2;
  unsigned short* wvT   = (unsigned short*)w; w += (size_t)1024 * KVRANK * 2;
  unsigned short* wprojT= (unsigned short*)w; w += (size_t)2048 * 1024 * 2;

  // ---- casts & weight transposes ----
  cast_to_bf16<<<ROWS * 2048 / (256 * 8), 256, 0, stream>>>(x, xb, ROWS * 2048);
  transpose_cast<<<dim3(QRANK / 32, 2048 / 32), 256, 0, stream>>>(w_cq, wcqT, 2048, QRANK);
  transpose_cast<<<dim3(1024 / 32, QRANK / 32), 256, 0, stream>>>(w_q_nope, wqnT, QRANK, 1024);
  transpose_cast<<<dim3(512 / 32, QRANK / 32), 256, 0, stream>>>(w_q_rope, wqrT, QRANK, 512);
  transpose_cast<<<dim3(KVRANK / 32, 2048 / 32), 256, 0, stream>>>(w_ckv, wckvT, 2048, KVRANK);
  transpose_cast<<<dim3(1024 / 32, KVRANK / 32), 256, 0, stream>>>(w_k_nope, wknT, KVRANK, 1024);
  transpose_cast<<<dim3(1024 / 32, KVRANK / 32), 256, 0, stream>>>(w_v, wvT, KVRANK, 1024);
  transpose_cast<<<dim3(2048 / 32, 1024 / 32), 256, 0, stream>>>(w_proj, wprojT, 1024, 2048);

  // ---- projections (bf16 MFMA) ----
  // cq = x @ w_cq  -> bf16, then rmsnorm in-place
  gemm_bf16<<<dim3(QRANK / 128, ROWS / 128), 256, 0, stream>>>(xb, wcqT, cqb, ROWS, QRANK, 2048, 1);
  rmsnorm_bf16<<<ROWS, 256, 0, stream>>>(cqb, q_g, QRANK, 1.0f / QRANK);
  // qn = cq @ w_q_nope (f32 out), qr = cq @ w_q_rope (f32 out)
  gemm_bf16<<<dim3(1024 / 128, ROWS / 128), 256, 0, stream>>>(cqb, wqnT, qn, ROWS, 1024, QRANK, 0);
  gemm_bf16<<<dim3(512 / 128, ROWS / 128), 256, 0, stream>>>(cqb, wqrT, qr, ROWS, 512, QRANK, 0);
  rope_q<<<ROWS, 256, 0, stream>>>(qr);
  // ckv = x @ w_ckv -> bf16, rmsnorm
  gemm_bf16<<<dim3(KVRANK / 128, ROWS / 128), 256, 0, stream>>>(xb, wckvT, ckvb, ROWS, KVRANK, 2048, 1);
  rmsnorm_bf16<<<ROWS, 256, 0, stream>>>(ckvb, kv_g, KVRANK, 1.0f / KVRANK);
  // kn, vv (f32 out)
  gemm_bf16<<<dim3(1024 / 128, ROWS / 128), 256, 0, stream>>>(ckvb, wknT, kn, ROWS, 1024, KVRANK, 0);
  gemm_bf16<<<dim3(1024 / 128, ROWS / 128), 256, 0, stream>>>(ckvb, wvT, vv, ROWS, 1024, KVRANK, 0);
  // k_rope (fp32 path)
  krope_kernel<<<ROWS, 256, 0, stream>>>(x, w_k_rope, kr);
  // attention -> bf16 ao
  attn_f32<<<dim3(32, B_ * H_), 256, 0, stream>>>(qn, qr, kn, kr, vv, aob);
  // out = ao @ w_proj (f32 out to d_out)
  gemm_bf16<<<dim3(2048 / 128, ROWS / 128), 256, 0, stream>>>(aob, wprojT, out, ROWS, 2048, 1024, 0);
}

// Round 4
// 435.378 us; speedup vs baseline: 4.1252x; 1.8155x over previous
//
#include <hip/hip_runtime.h>
#include <hip/hip_bf16.h>
#include <math.h>

#define B_      2
#define S_      2048
#define D_      2048
#define H_      16
#define NOPE_D  64
#define ROPE_DD 32
#define V_DD    64
#define QRANK   768
#define KVRANK  256
#define ROWS    (B_ * S_)   // 4096

typedef __attribute__((ext_vector_type(8))) short short8;
typedef __attribute__((ext_vector_type(4))) float f32x4;
typedef __attribute__((ext_vector_type(4))) unsigned short ushort4v;

__device__ __forceinline__ float bf2f(unsigned short u) {
  return __uint_as_float(((unsigned)u) << 16);
}
__device__ __forceinline__ unsigned short f2bf(float f) {  // RNE
  unsigned u = __float_as_uint(f);
  return (unsigned short)((u + 0x7fffu + ((u >> 16) & 1u)) >> 16);
}

// ---------------------------------------------------------------------------
// cast fp32 -> bf16, 8 elems/thread
// ---------------------------------------------------------------------------
__global__ __launch_bounds__(256) void cast_to_bf16(const float* __restrict__ in,
                                                    unsigned short* __restrict__ out,
                                                    int n) {
  int i = (blockIdx.x * 256 + threadIdx.x) * 8;
  if (i >= n) return;
  float4 a = *(const float4*)(in + i);
  float4 b = *(const float4*)(in + i + 4);
  unsigned short r[8] = {f2bf(a.x), f2bf(a.y), f2bf(a.z), f2bf(a.w),
                         f2bf(b.x), f2bf(b.y), f2bf(b.z), f2bf(b.w)};
  *(ushort4v*)(out + i)     = *(ushort4v*)&r[0];
  *(ushort4v*)(out + i + 4) = *(ushort4v*)&r[4];
}

// ---------------------------------------------------------------------------
// transpose + cast: in [R][C] fp32 -> out [C][R] bf16.  R,C % 32 == 0.
// ---------------------------------------------------------------------------
__global__ __launch_bounds__(256) void transpose_cast(const float* __restrict__ in,
                                                      unsigned short* __restrict__ out,
                                                      int R, int C) {
  __shared__ unsigned short t[32][33];
  const int c0 = blockIdx.x * 32, r0 = blockIdx.y * 32;
  const int tx = threadIdx.x & 31, ty = threadIdx.x >> 5;  // ty 0..7
#pragma unroll
  for (int i = 0; i < 32; i += 8)
    t[ty + i][tx] = f2bf(in[(size_t)(r0 + ty + i) * C + c0 + tx]);
  __syncthreads();
#pragma unroll
  for (int i = 0; i < 32; i += 8)
    out[(size_t)(c0 + ty + i) * R + r0 + tx] = t[tx][ty + i];
}

// ---------------------------------------------------------------------------
// transpose bf16: in [R][C] -> out [C][R]
// ---------------------------------------------------------------------------
__global__ __launch_bounds__(256) void transpose_bf16(const unsigned short* __restrict__ in,
                                                      unsigned short* __restrict__ out,
                                                      int R, int C) {
  __shared__ unsigned short t[32][33];
  const int c0 = blockIdx.x * 32, r0 = blockIdx.y * 32;
  const int tx = threadIdx.x & 31, ty = threadIdx.x >> 5;
#pragma unroll
  for (int i = 0; i < 32; i += 8)
    t[ty + i][tx] = in[(size_t)(r0 + ty + i) * C + c0 + tx];
  __syncthreads();
#pragma unroll
  for (int i = 0; i < 32; i += 8)
    out[(size_t)(c0 + ty + i) * R + r0 + tx] = t[tx][ty + i];
}

// ---------------------------------------------------------------------------
// bf16 MFMA GEMM (TN): A [M][K] bf16, Bt [N][K] bf16, C [M][N] (f32 or bf16).
// M%128==0, N%128==0, K%32==0. 256 thr = 4 waves, tile 128x128, BK=32.
// ---------------------------------------------------------------------------
__global__ __launch_bounds__(256) void gemm_bf16(const unsigned short* __restrict__ A,
                                                 const unsigned short* __restrict__ Bt,
                                                 void* __restrict__ Cv,
                                                 int M, int N, int K, int c_bf16) {
  __shared__ unsigned short As[128 * 32];
  __shared__ unsigned short Bs[128 * 32];
  const int tid = threadIdx.x;
  const int lane = tid & 63;
  const int wave = tid >> 6;
  const int wm = (wave >> 1) << 6;
  const int wn = (wave & 1) << 6;
  const int m0 = blockIdx.y * 128, n0 = blockIdx.x * 128;

  const int srow = tid >> 1;
  const int sg = (tid & 1) * 2;
  const size_t a_base = (size_t)(m0 + srow) * K + sg * 8;
  const size_t b_base = (size_t)(n0 + srow) * K + sg * 8;
  const int w0 = srow * 64 + ((sg ^ (srow & 3)) << 4);
  const int w1 = srow * 64 + (((sg + 1) ^ (srow & 3)) << 4);

  const int frow = lane & 15, fg = lane >> 4;
  int a_roff[4], b_roff[4];
#pragma unroll
  for (int m = 0; m < 4; ++m) {
    int r = wm + m * 16 + frow;
    a_roff[m] = r * 64 + ((fg ^ (r & 3)) << 4);
  }
#pragma unroll
  for (int n = 0; n < 4; ++n) {
    int r = wn + n * 16 + frow;
    b_roff[n] = r * 64 + ((fg ^ (r & 3)) << 4);
  }

  f32x4 acc[4][4];
#pragma unroll
  for (int m = 0; m < 4; ++m)
#pragma unroll
    for (int n = 0; n < 4; ++n) acc[m][n] = (f32x4){0.f, 0.f, 0.f, 0.f};

  for (int k0 = 0; k0 < K; k0 += 32) {
    uint4 va  = *(const uint4*)(A + a_base + k0);
    uint4 va2 = *(const uint4*)(A + a_base + k0 + 8);
    uint4 vb  = *(const uint4*)(Bt + b_base + k0);
    uint4 vb2 = *(const uint4*)(Bt + b_base + k0 + 8);
    __syncthreads();
    *(uint4*)((char*)As + w0) = va;
    *(uint4*)((char*)As + w1) = va2;
    *(uint4*)((char*)Bs + w0) = vb;
    *(uint4*)((char*)Bs + w1) = vb2;
    __syncthreads();
    short8 af[4], bfr[4];
#pragma unroll
    for (int m = 0; m < 4; ++m) af[m] = *(const short8*)((const char*)As + a_roff[m]);
#pragma unroll
    for (int n = 0; n < 4; ++n) bfr[n] = *(const short8*)((const char*)Bs + b_roff[n]);
#pragma unroll
    for (int m = 0; m < 4; ++m)
#pragma unroll
      for (int n = 0; n < 4; ++n)
        acc[m][n] = __builtin_amdgcn_mfma_f32_16x16x32_bf16(af[m], bfr[n], acc[m][n], 0, 0, 0);
  }

  const int crow = (lane >> 4) * 4;
  const int ccol = lane & 15;
  if (c_bf16) {
    unsigned short* Cb = (unsigned short*)Cv;
#pragma unroll
    for (int m = 0; m < 4; ++m)
#pragma unroll
      for (int n = 0; n < 4; ++n)
#pragma unroll
        for (int r = 0; r < 4; ++r)
          Cb[(size_t)(m0 + wm + m * 16 + crow + r) * N + n0 + wn + n * 16 + ccol] =
              f2bf(acc[m][n][r]);
  } else {
    float* Cf = (float*)Cv;
#pragma unroll
    for (int m = 0; m < 4; ++m)
#pragma unroll
      for (int n = 0; n < 4; ++n)
#pragma unroll
        for (int r = 0; r < 4; ++r)
          Cf[(size_t)(m0 + wm + m * 16 + crow + r) * N + n0 + wn + n * 16 + ccol] =
              acc[m][n][r];
  }
}

// ---------------------------------------------------------------------------
// In-place RMSNorm on bf16 buffer
// ---------------------------------------------------------------------------
__global__ __launch_bounds__(256) void rmsnorm_bf16(unsigned short* __restrict__ x,
                                                    const float* __restrict__ g,
                                                    int cols, float inv_cols) {
  const int row = blockIdx.x;
  unsigned short* p = x + (size_t)row * cols;
  float ss = 0.f;
  for (int c = threadIdx.x; c < cols; c += 256) { float v = bf2f(p[c]); ss += v * v; }
#pragma unroll
  for (int off = 32; off >= 1; off >>= 1) ss += __shfl_xor(ss, off, 64);
  __shared__ float wsum[4];
  if ((threadIdx.x & 63) == 0) wsum[threadIdx.x >> 6] = ss;
  __syncthreads();
  float tot = (wsum[0] + wsum[1]) + (wsum[2] + wsum[3]);
  float r = rsqrtf(tot * inv_cols + 1e-6f);
  for (int c = threadIdx.x; c < cols; c += 256) p[c] = f2bf(bf2f(p[c]) * r * g[c]);
}

// ---------------------------------------------------------------------------
// RoPE on bf16 q_rope [4096][512]. Reference's sin table == cos table.
// ---------------------------------------------------------------------------
__global__ __launch_bounds__(256) void rope_q_bf16(unsigned short* __restrict__ qr) {
  const int row = blockIdx.x;
  const int t = threadIdx.x;
  const int h = t >> 4, i = t & 15;
  const int pos = row & (S_ - 1);
  float freq = powf(10000.0f, -(float)i / 16.0f);
  float c = cosf((float)pos * freq);
  unsigned* p = (unsigned*)(qr + (size_t)row * 512 + h * 32 + 2 * i);
  unsigned v = *p;
  float xr = bf2f((unsigned short)(v & 0xffffu));
  float xi = bf2f((unsigned short)(v >> 16));
  unsigned short o0 = f2bf((xr - xi) * c);
  unsigned short o1 = f2bf((xr + xi) * c);
  *p = (unsigned)o0 | ((unsigned)o1 << 16);
}

// ---------------------------------------------------------------------------
// k_rope: krb[row][0:32] = bf16( rope( (x[row] @ w_k_rope) / H ) )
// ---------------------------------------------------------------------------
__global__ __launch_bounds__(256) void krope_kernel(const float* __restrict__ x,
                                                    const float* __restrict__ w,
                                                    unsigned short* __restrict__ krb) {
  __shared__ float xs[2048];
  __shared__ float part[8][33];
  __shared__ float vals[32];
  const int row = blockIdx.x;
  const int t = threadIdx.x;
  const float* xp = x + (size_t)row * D_;
#pragma unroll
  for (int i = 0; i < 2; ++i) {
    int idx = t * 4 + i * 1024;
    *(float4*)&xs[idx] = *(const float4*)&xp[idx];
  }
  __syncthreads();
  const int c = t & 31, j = t >> 5;
  float s = 0.f;
  for (int k = j; k < D_; k += 8) s = fmaf(xs[k], w[k * 32 + c], s);
  part[j][c] = s;
  __syncthreads();
  if (t < 32) {
    float tot = 0.f;
#pragma unroll
    for (int jj = 0; jj < 8; ++jj) tot += part[jj][t];
    vals[t] = tot * (1.0f / (float)H_);
  }
  __syncthreads();
  if (t < 16) {
    const int pos = row & (S_ - 1);
    float freq = powf(10000.0f, -(float)t / 16.0f);
    float cc = cosf((float)pos * freq);
    float xr = vals[2 * t], xi = vals[2 * t + 1];
    krb[(size_t)row * 32 + 2 * t]     = f2bf((xr - xi) * cc);
    krb[(size_t)row * 32 + 2 * t + 1] = f2bf((xr + xi) * cc);
  }
}

// ---------------------------------------------------------------------------
// MFMA flash attention, bf16 inputs, f32 softmax/accum.
// Block: 256 thr = 4 waves; q-tile 64 rows (wave w owns rows w*16..w*16+16);
// k-tiles of 64. Diagonal pairing: block p does q-tiles {p, 31-p} (33 iters).
// QK^T: TN-mfma over 96 dims (3 k-steps). Softmax in regs (16-lane shfl).
// P (bf16) -> wave-private LDS rows; PV: TN-mfma with pre-transposed V tile.
// Scale 1/sqrt(96) folded into exp2 constant.
// ---------------------------------------------------------------------------
#define QK_STRIDE 104   // 96 data + pad; 208B row, 2-way bank max
#define PV_STRIDE 72    // 64 data + pad; 144B row

__global__ __launch_bounds__(256) void attn_mfma(
    const unsigned short* __restrict__ qnb,  // [4096][1024]
    const unsigned short* __restrict__ qrb,  // [4096][512]
    const unsigned short* __restrict__ knb,  // [4096][1024]
    const unsigned short* __restrict__ krb,  // [4096][32]
    const unsigned short* __restrict__ vvT,  // [1024][4096]: [h*64+d][b*2048+s]
    unsigned short* __restrict__ aob) {      // [4096][1024]
  __shared__ unsigned short Qs[64 * QK_STRIDE];
  __shared__ unsigned short Ks[64 * QK_STRIDE];
  __shared__ unsigned short Vt[64 * PV_STRIDE];
  __shared__ unsigned short Ps[64 * PV_STRIDE];
  const int tid = threadIdx.x;
  const int lane = tid & 63;
  const int wave = tid >> 6;
  const int bh = blockIdx.y;
  const int b = bh >> 4, h = bh & 15;
  const size_t rowbase = (size_t)b * S_;
  const int frow = lane & 15, fg = lane >> 4;
  const int ccol = lane & 15, crow = (lane >> 4) * 4;
  const float C2 = 0.10206207261596575f * 1.4426950408889634f;  // scale*log2(e)

  for (int half = 0; half < 2; ++half) {
    const int q0 = (half ? (31 - blockIdx.x) : blockIdx.x) * 64;
    __syncthreads();  // previous half's Qs reads complete
    {  // load Q tile: nope 64 + rope 32 bf16 per row
      int g = tid;
#pragma unroll
      for (int rep = 0; rep < 2; ++rep, g += 256) {
        int row = g >> 3, col = (g & 7) * 8;
        *(uint4*)&Qs[row * QK_STRIDE + col] =
            *(const uint4*)&qnb[(size_t)(rowbase + q0 + row) * 1024 + (h << 6) + col];
      }
      int row = tid >> 2, col = (tid & 3) * 8;
      *(uint4*)&Qs[row * QK_STRIDE + 64 + col] =
          *(const uint4*)&qrb[(size_t)(rowbase + q0 + row) * 512 + (h << 5) + col];
    }

    float m[4] = {-1e30f, -1e30f, -1e30f, -1e30f};
    float l[4] = {0.f, 0.f, 0.f, 0.f};
    f32x4 acc_o[4];
#pragma unroll
    for (int n = 0; n < 4; ++n) acc_o[n] = (f32x4){0.f, 0.f, 0.f, 0.f};

    for (int k0 = 0; k0 <= q0; k0 += 64) {
      __syncthreads();  // prev iter's Ks/Vt reads (and Qs write on iter 0) done
      {  // load K tile + Vt tile
        int g = tid;
#pragma unroll
        for (int rep = 0; rep < 2; ++rep, g += 256) {
          int row = g >> 3, col = (g & 7) * 8;
          *(uint4*)&Ks[row * QK_STRIDE + col] =
              *(const uint4*)&knb[(size_t)(rowbase + k0 + row) * 1024 + (h << 6) + col];
          *(uint4*)&Vt[row * PV_STRIDE + col] =
              *(const uint4*)&vvT[(size_t)((h << 6) + row) * 4096 + b * S_ + k0 + col];
        }
        int row = tid >> 2, col = (tid & 3) * 8;
        *(uint4*)&Ks[row * QK_STRIDE + 64 + col] =
            *(const uint4*)&krb[(size_t)(rowbase + k0 + row) * 32 + col];
      }
      __syncthreads();

      // ---- QK^T ----
      f32x4 sa[4];
#pragma unroll
      for (int n = 0; n < 4; ++n) sa[n] = (f32x4){0.f, 0.f, 0.f, 0.f};
#pragma unroll
      for (int c = 0; c < 3; ++c) {
        short8 aq = *(const short8*)&Qs[(wave * 16 + frow) * QK_STRIDE + c * 32 + fg * 8];
#pragma unroll
        for (int n = 0; n < 4; ++n) {
          short8 bk = *(const short8*)&Ks[(n * 16 + frow) * QK_STRIDE + c * 32 + fg * 8];
          sa[n] = __builtin_amdgcn_mfma_f32_16x16x32_bf16(aq, bk, sa[n], 0, 0, 0);
        }
      }
      if (k0 == q0) {  // diagonal tile: mask k > q
#pragma unroll
        for (int n = 0; n < 4; ++n) {
          int kg = n * 16 + ccol;
#pragma unroll
          for (int r = 0; r < 4; ++r)
            if (kg > wave * 16 + crow + r) sa[n][r] = -1e30f;
        }
      }
      // ---- online softmax (raw scores; scale folded into C2) ----
      float mx[4];
#pragma unroll
      for (int r = 0; r < 4; ++r) {
        mx[r] = fmaxf(fmaxf(sa[0][r], sa[1][r]), fmaxf(sa[2][r], sa[3][r]));
#pragma unroll
        for (int off = 1; off <= 8; off <<= 1)
          mx[r] = fmaxf(mx[r], __shfl_xor(mx[r], off, 64));
      }
      int nogrow = (mx[0] <= m[0]) & (mx[1] <= m[1]) & (mx[2] <= m[2]) & (mx[3] <= m[3]);
      if (!__all(nogrow)) {
#pragma unroll
        for (int r = 0; r < 4; ++r) {
          float mn = fmaxf(m[r], mx[r]);
          float ra = exp2f((m[r] - mn) * C2);
          m[r] = mn;
          l[r] *= ra;
#pragma unroll
          for (int n = 0; n < 4; ++n) acc_o[n][r] *= ra;
        }
      }
      float p[4][4];
#pragma unroll
      for (int r = 0; r < 4; ++r) {
        float rs = 0.f;
#pragma unroll
        for (int n = 0; n < 4; ++n) {
          p[n][r] = exp2f((sa[n][r] - m[r]) * C2);
          rs += p[n][r];
        }
#pragma unroll
        for (int off = 1; off <= 8; off <<= 1) rs += __shfl_xor(rs, off, 64);
        l[r] += rs;
      }
      // ---- P -> LDS (wave-private rows), then PV ----
#pragma unroll
      for (int n = 0; n < 4; ++n)
#pragma unroll
        for (int r = 0; r < 4; ++r)
          Ps[(wave * 16 + crow + r) * PV_STRIDE + n * 16 + ccol] = f2bf(p[n][r]);
      __builtin_amdgcn_wave_barrier();
#pragma unroll
      for (int c = 0; c < 2; ++c) {
        short8 ap = *(const short8*)&Ps[(wave * 16 + frow) * PV_STRIDE + c * 32 + fg * 8];
#pragma unroll
        for (int n = 0; n < 4; ++n) {
          short8 bv = *(const short8*)&Vt[(n * 16 + frow) * PV_STRIDE + c * 32 + fg * 8];
          acc_o[n] = __builtin_amdgcn_mfma_f32_16x16x32_bf16(ap, bv, acc_o[n], 0, 0, 0);
        }
      }
      __builtin_amdgcn_wave_barrier();
    }
    // ---- epilogue ----
    float inv[4];
#pragma unroll
    for (int r = 0; r < 4; ++r) inv[r] = 1.f / l[r];
#pragma unroll
    for (int n = 0; n < 4; ++n)
#pragma unroll
      for (int r = 0; r < 4; ++r)
        aob[(size_t)(rowbase + q0 + wave * 16 + crow + r) * 1024 + (h << 6) + n * 16 + ccol] =
            f2bf(acc_o[n][r] * inv[r]);
  }
}

// ---------------------------------------------------------------------------
extern "C" void kernel_launch(void* const* d_in, const int* in_sizes, int n_in,
                              void* d_out, int out_size, void* d_ws, size_t ws_size,
                              hipStream_t stream) {
  const float* x        = (const float*)d_in[0];
  const float* w_cq     = (const float*)d_in[1];
  const float* w_q_nope = (const float*)d_in[2];
  const float* w_q_rope = (const float*)d_in[3];
  const float* q_g      = (const float*)d_in[4];
  const float* w_ckv    = (const float*)d_in[5];
  const float* w_k_nope = (const float*)d_in[6];
  const float* w_v      = (const float*)d_in[7];
  const float* kv_g     = (const float*)d_in[8];
  const float* w_k_rope = (const float*)d_in[9];
  const float* w_proj   = (const float*)d_in[10];
  float* out = (float*)d_out;

  // ---- workspace layout (all bf16 except noted) ----
  char* w = (char*)d_ws;
  unsigned short* xb    = (unsigned short*)w; w += (size_t)ROWS * 2048 * 2;
  unsigned short* cqb   = (unsigned short*)w; w += (size_t)ROWS * QRANK * 2;
  unsigned short* ckvb  = (unsigned short*)w; w += (size_t)ROWS * KVRANK * 2;
  unsigned short* qnb   = (unsigned short*)w; w += (size_t)ROWS * 1024 * 2;
  unsigned short* qrb   = (unsigned short*)w; w += (size_t)ROWS * 512 * 2;
  unsigned short* knb   = (unsigned short*)w; w += (size_t)ROWS * 1024 * 2;
  unsigned short* vvb   = (unsigned short*)w; w += (size_t)ROWS * 1024 * 2;
  unsigned short* vvT   = (unsigned short*)w; w += (size_t)1024 * ROWS * 2;
  unsigned short* krb   = (unsigned short*)w; w += (size_t)ROWS * 32 * 2;
  unsigned short* aob   = (unsigned short*)w; w += (size_t)ROWS * 1024 * 2;
  unsigned short* wcqT  = (unsigned short*)w; w += (size_t)QRANK * 2048 * 2;
  unsigned short* wqnT  = (unsigned short*)w; w += (size_t)1024 * QRANK * 2;
  unsigned short* wqrT  = (unsigned short*)w; w += (size_t)512 * QRANK * 2;
  unsigned short* wckvT = (unsigned short*)w; w += (size_t)KVRANK * 2048 * 2;
  unsigned short* wknT  = (unsigned short*)w; w += (size_t)1024 * KVRANK * 2;
  unsigned short* wvT   = (unsigned short*)w; w += (size_t)1024 * KVRANK * 2;
  unsigned short* wprojT= (unsigned short*)w; w += (size_t)2048 * 1024 * 2;

  // ---- casts & weight transposes ----
  cast_to_bf16<<<ROWS * 2048 / (256 * 8), 256, 0, stream>>>(x, xb, ROWS * 2048);
  transpose_cast<<<dim3(QRANK / 32, 2048 / 32), 256, 0, stream>>>(w_cq, wcqT, 2048, QRANK);
  transpose_cast<<<dim3(1024 / 32, QRANK / 32), 256, 0, stream>>>(w_q_nope, wqnT, QRANK, 1024);
  transpose_cast<<<dim3(512 / 32, QRANK / 32), 256, 0, stream>>>(w_q_rope, wqrT, QRANK, 512);
  transpose_cast<<<dim3(KVRANK / 32, 2048 / 32), 256, 0, stream>>>(w_ckv, wckvT, 2048, KVRANK);
  transpose_cast<<<dim3(1024 / 32, KVRANK / 32), 256, 0, stream>>>(w_k_nope, wknT, KVRANK, 1024);
  transpose_cast<<<dim3(1024 / 32, KVRANK / 32), 256, 0, stream>>>(w_v, wvT, KVRANK, 1024);
  transpose_cast<<<dim3(2048 / 32, 1024 / 32), 256, 0, stream>>>(w_proj, wprojT, 1024, 2048);

  // ---- projections (bf16 MFMA, bf16 outputs) ----
  gemm_bf16<<<dim3(QRANK / 128, ROWS / 128), 256, 0, stream>>>(xb, wcqT, cqb, ROWS, QRANK, 2048, 1);
  rmsnorm_bf16<<<ROWS, 256, 0, stream>>>(cqb, q_g, QRANK, 1.0f / QRANK);
  gemm_bf16<<<dim3(1024 / 128, ROWS / 128), 256, 0, stream>>>(cqb, wqnT, qnb, ROWS, 1024, QRANK, 1);
  gemm_bf16<<<dim3(512 / 128, ROWS / 128), 256, 0, stream>>>(cqb, wqrT, qrb, ROWS, 512, QRANK, 1);
  rope_q_bf16<<<ROWS, 256, 0, stream>>>(qrb);
  gemm_bf16<<<dim3(KVRANK / 128, ROWS / 128), 256, 0, stream>>>(xb, wckvT, ckvb, ROWS, KVRANK, 2048, 1);
  rmsnorm_bf16<<<ROWS, 256, 0, stream>>>(ckvb, kv_g, KVRANK, 1.0f / KVRANK);
  gemm_bf16<<<dim3(1024 / 128, ROWS / 128), 256, 0, stream>>>(ckvb, wknT, knb, ROWS, 1024, KVRANK, 1);
  gemm_bf16<<<dim3(1024 / 128, ROWS / 128), 256, 0, stream>>>(ckvb, wvT, vvb, ROWS, 1024, KVRANK, 1);
  transpose_bf16<<<dim3(1024 / 32, ROWS / 32), 256, 0, stream>>>(vvb, vvT, ROWS, 1024);
  krope_kernel<<<ROWS, 256, 0, stream>>>(x, w_k_rope, krb);

  // ---- attention (MFMA flash) ----
  attn_mfma<<<dim3(16, 32), 256, 0, stream>>>(qnb, qrb, knb, krb, vvT, aob);

  // ---- output projection ----
  gemm_bf16<<<dim3(2048 / 128, ROWS / 128), 256, 0, stream>>>(aob, wprojT, out, ROWS, 2048, 1024, 0);
}

// Round 5
// 366.340 us; speedup vs baseline: 4.9026x; 1.1885x over previous
//
#include <hip/hip_runtime.h>
#include <hip/hip_bf16.h>
#include <math.h>

#define B_      2
#define S_      2048
#define D_      2048
#define H_      16
#define NOPE_D  64
#define ROPE_DD 32
#define V_DD    64
#define QRANK   768
#define KVRANK  256
#define ROWS    (B_ * S_)   // 4096

typedef __attribute__((ext_vector_type(8))) short short8;
typedef __attribute__((ext_vector_type(4))) float f32x4;
typedef __attribute__((ext_vector_type(4))) unsigned short ushort4v;

__device__ __forceinline__ float bf2f(unsigned short u) {
  return __uint_as_float(((unsigned)u) << 16);
}
__device__ __forceinline__ unsigned short f2bf(float f) {  // RNE
  unsigned u = __float_as_uint(f);
  return (unsigned short)((u + 0x7fffu + ((u >> 16) & 1u)) >> 16);
}

// ---------------------------------------------------------------------------
// cast fp32 -> bf16, 8 elems/thread
// ---------------------------------------------------------------------------
__global__ __launch_bounds__(256) void cast_to_bf16(const float* __restrict__ in,
                                                    unsigned short* __restrict__ out,
                                                    int n) {
  int i = (blockIdx.x * 256 + threadIdx.x) * 8;
  if (i >= n) return;
  float4 a = *(const float4*)(in + i);
  float4 b = *(const float4*)(in + i + 4);
  unsigned short r[8] = {f2bf(a.x), f2bf(a.y), f2bf(a.z), f2bf(a.w),
                         f2bf(b.x), f2bf(b.y), f2bf(b.z), f2bf(b.w)};
  *(ushort4v*)(out + i)     = *(ushort4v*)&r[0];
  *(ushort4v*)(out + i + 4) = *(ushort4v*)&r[4];
}

// ---------------------------------------------------------------------------
// transpose + cast: in [R][C] fp32 -> out [C][R] bf16.  R,C % 32 == 0.
// ---------------------------------------------------------------------------
__global__ __launch_bounds__(256) void transpose_cast(const float* __restrict__ in,
                                                      unsigned short* __restrict__ out,
                                                      int R, int C) {
  __shared__ unsigned short t[32][33];
  const int c0 = blockIdx.x * 32, r0 = blockIdx.y * 32;
  const int tx = threadIdx.x & 31, ty = threadIdx.x >> 5;  // ty 0..7
#pragma unroll
  for (int i = 0; i < 32; i += 8)
    t[ty + i][tx] = f2bf(in[(size_t)(r0 + ty + i) * C + c0 + tx]);
  __syncthreads();
#pragma unroll
  for (int i = 0; i < 32; i += 8)
    out[(size_t)(c0 + ty + i) * R + r0 + tx] = t[tx][ty + i];
}

// ---------------------------------------------------------------------------
// transpose bf16: in [R][C] -> out [C][R]
// ---------------------------------------------------------------------------
__global__ __launch_bounds__(256) void transpose_bf16(const unsigned short* __restrict__ in,
                                                      unsigned short* __restrict__ out,
                                                      int R, int C) {
  __shared__ unsigned short t[32][33];
  const int c0 = blockIdx.x * 32, r0 = blockIdx.y * 32;
  const int tx = threadIdx.x & 31, ty = threadIdx.x >> 5;
#pragma unroll
  for (int i = 0; i < 32; i += 8)
    t[ty + i][tx] = in[(size_t)(r0 + ty + i) * C + c0 + tx];
  __syncthreads();
#pragma unroll
  for (int i = 0; i < 32; i += 8)
    out[(size_t)(c0 + ty + i) * R + r0 + tx] = t[tx][ty + i];
}

// ---------------------------------------------------------------------------
// bf16 MFMA GEMM (TN): A [M][K] bf16, Bt [N][K] bf16, C [M][N] (f32 or bf16).
// M%128==0, N%128==0, K%32==0. 256 thr = 4 waves, tile 128x128, BK=32.
// ---------------------------------------------------------------------------
__global__ __launch_bounds__(256) void gemm_bf16(const unsigned short* __restrict__ A,
                                                 const unsigned short* __restrict__ Bt,
                                                 void* __restrict__ Cv,
                                                 int M, int N, int K, int c_bf16) {
  __shared__ unsigned short As[128 * 32];
  __shared__ unsigned short Bs[128 * 32];
  const int tid = threadIdx.x;
  const int lane = tid & 63;
  const int wave = tid >> 6;
  const int wm = (wave >> 1) << 6;
  const int wn = (wave & 1) << 6;
  const int m0 = blockIdx.y * 128, n0 = blockIdx.x * 128;

  const int srow = tid >> 1;
  const int sg = (tid & 1) * 2;
  const size_t a_base = (size_t)(m0 + srow) * K + sg * 8;
  const size_t b_base = (size_t)(n0 + srow) * K + sg * 8;
  const int w0 = srow * 64 + ((sg ^ (srow & 3)) << 4);
  const int w1 = srow * 64 + (((sg + 1) ^ (srow & 3)) << 4);

  const int frow = lane & 15, fg = lane >> 4;
  int a_roff[4], b_roff[4];
#pragma unroll
  for (int m = 0; m < 4; ++m) {
    int r = wm + m * 16 + frow;
    a_roff[m] = r * 64 + ((fg ^ (r & 3)) << 4);
  }
#pragma unroll
  for (int n = 0; n < 4; ++n) {
    int r = wn + n * 16 + frow;
    b_roff[n] = r * 64 + ((fg ^ (r & 3)) << 4);
  }

  f32x4 acc[4][4];
#pragma unroll
  for (int m = 0; m < 4; ++m)
#pragma unroll
    for (int n = 0; n < 4; ++n) acc[m][n] = (f32x4){0.f, 0.f, 0.f, 0.f};

  for (int k0 = 0; k0 < K; k0 += 32) {
    uint4 va  = *(const uint4*)(A + a_base + k0);
    uint4 va2 = *(const uint4*)(A + a_base + k0 + 8);
    uint4 vb  = *(const uint4*)(Bt + b_base + k0);
    uint4 vb2 = *(const uint4*)(Bt + b_base + k0 + 8);
    __syncthreads();
    *(uint4*)((char*)As + w0) = va;
    *(uint4*)((char*)As + w1) = va2;
    *(uint4*)((char*)Bs + w0) = vb;
    *(uint4*)((char*)Bs + w1) = vb2;
    __syncthreads();
    short8 af[4], bfr[4];
#pragma unroll
    for (int m = 0; m < 4; ++m) af[m] = *(const short8*)((const char*)As + a_roff[m]);
#pragma unroll
    for (int n = 0; n < 4; ++n) bfr[n] = *(const short8*)((const char*)Bs + b_roff[n]);
#pragma unroll
    for (int m = 0; m < 4; ++m)
#pragma unroll
      for (int n = 0; n < 4; ++n)
        acc[m][n] = __builtin_amdgcn_mfma_f32_16x16x32_bf16(af[m], bfr[n], acc[m][n], 0, 0, 0);
  }

  const int crow = (lane >> 4) * 4;
  const int ccol = lane & 15;
  if (c_bf16) {
    unsigned short* Cb = (unsigned short*)Cv;
#pragma unroll
    for (int m = 0; m < 4; ++m)
#pragma unroll
      for (int n = 0; n < 4; ++n)
#pragma unroll
        for (int r = 0; r < 4; ++r)
          Cb[(size_t)(m0 + wm + m * 16 + crow + r) * N + n0 + wn + n * 16 + ccol] =
              f2bf(acc[m][n][r]);
  } else {
    float* Cf = (float*)Cv;
#pragma unroll
    for (int m = 0; m < 4; ++m)
#pragma unroll
      for (int n = 0; n < 4; ++n)
#pragma unroll
        for (int r = 0; r < 4; ++r)
          Cf[(size_t)(m0 + wm + m * 16 + crow + r) * N + n0 + wn + n * 16 + ccol] =
              acc[m][n][r];
  }
}

// ---------------------------------------------------------------------------
// In-place RMSNorm on bf16 buffer
// ---------------------------------------------------------------------------
__global__ __launch_bounds__(256) void rmsnorm_bf16(unsigned short* __restrict__ x,
                                                    const float* __restrict__ g,
                                                    int cols, float inv_cols) {
  const int row = blockIdx.x;
  unsigned short* p = x + (size_t)row * cols;
  float ss = 0.f;
  for (int c = threadIdx.x; c < cols; c += 256) { float v = bf2f(p[c]); ss += v * v; }
#pragma unroll
  for (int off = 32; off >= 1; off >>= 1) ss += __shfl_xor(ss, off, 64);
  __shared__ float wsum[4];
  if ((threadIdx.x & 63) == 0) wsum[threadIdx.x >> 6] = ss;
  __syncthreads();
  float tot = (wsum[0] + wsum[1]) + (wsum[2] + wsum[3]);
  float r = rsqrtf(tot * inv_cols + 1e-6f);
  for (int c = threadIdx.x; c < cols; c += 256) p[c] = f2bf(bf2f(p[c]) * r * g[c]);
}

// ---------------------------------------------------------------------------
// RoPE on bf16 q_rope [4096][512]. Reference's sin table == cos table.
// ---------------------------------------------------------------------------
__global__ __launch_bounds__(256) void rope_q_bf16(unsigned short* __restrict__ qr) {
  const int row = blockIdx.x;
  const int t = threadIdx.x;
  const int h = t >> 4, i = t & 15;
  const int pos = row & (S_ - 1);
  float freq = powf(10000.0f, -(float)i / 16.0f);
  float c = cosf((float)pos * freq);
  unsigned* p = (unsigned*)(qr + (size_t)row * 512 + h * 32 + 2 * i);
  unsigned v = *p;
  float xr = bf2f((unsigned short)(v & 0xffffu));
  float xi = bf2f((unsigned short)(v >> 16));
  unsigned short o0 = f2bf((xr - xi) * c);
  unsigned short o1 = f2bf((xr + xi) * c);
  *p = (unsigned)o0 | ((unsigned)o1 << 16);
}

// ---------------------------------------------------------------------------
// k_rope as MFMA GEMM + fused rope epilogue:
// krb[row][0:32] = bf16( rope( (xb[row] @ wkrT^T) / H ) )
// BM=64, BN=32, BK=64; 4 waves (wave w owns rows w*16..w*16+16, all 32 cols).
// Rope pairs (2i,2i+1) live in adjacent lanes -> shfl_xor(v,1).
// ---------------------------------------------------------------------------
__global__ __launch_bounds__(256) void gemm_kr_rope(
    const unsigned short* __restrict__ xb,   // [4096][2048]
    const unsigned short* __restrict__ wkrT, // [32][2048]
    unsigned short* __restrict__ krb) {      // [4096][32]
  __shared__ unsigned short As[64 * 64];   // 8 KB, granule-XOR-swizzled
  __shared__ unsigned short Bs[32 * 64];   // 4 KB
  const int tid = threadIdx.x;
  const int lane = tid & 63;
  const int wave = tid >> 6;
  const int m0 = blockIdx.x * 64;
  const int frow = lane & 15, fg = lane >> 4;

  // A staging: thread t -> row t>>2, granules {(t&3)*2, (t&3)*2+1}
  const int arow = tid >> 2;
  const int ag = (tid & 3) * 2;
  // B staging: thread t -> row t>>3, granule t&7
  const int brow = tid >> 3;
  const int bg = tid & 7;

  f32x4 acc[2];
  acc[0] = (f32x4){0.f, 0.f, 0.f, 0.f};
  acc[1] = (f32x4){0.f, 0.f, 0.f, 0.f};

  for (int k0 = 0; k0 < 2048; k0 += 64) {
    uint4 va0 = *(const uint4*)&xb[(size_t)(m0 + arow) * 2048 + k0 + ag * 8];
    uint4 va1 = *(const uint4*)&xb[(size_t)(m0 + arow) * 2048 + k0 + ag * 8 + 8];
    uint4 vb  = *(const uint4*)&wkrT[(size_t)brow * 2048 + k0 + bg * 8];
    __syncthreads();
    *(uint4*)((char*)As + arow * 128 + ((ag ^ (arow & 7)) << 4))       = va0;
    *(uint4*)((char*)As + arow * 128 + (((ag + 1) ^ (arow & 7)) << 4)) = va1;
    *(uint4*)((char*)Bs + brow * 128 + ((bg ^ (brow & 7)) << 4))       = vb;
    __syncthreads();
#pragma unroll
    for (int kk = 0; kk < 2; ++kk) {
      const int ar = wave * 16 + frow;
      short8 aq = *(const short8*)((const char*)As + ar * 128 + (((kk * 4 + fg) ^ (ar & 7)) << 4));
#pragma unroll
      for (int n = 0; n < 2; ++n) {
        const int br = n * 16 + frow;
        short8 bk = *(const short8*)((const char*)Bs + br * 128 + (((kk * 4 + fg) ^ (br & 7)) << 4));
        acc[n] = __builtin_amdgcn_mfma_f32_16x16x32_bf16(aq, bk, acc[n], 0, 0, 0);
      }
    }
  }
  // epilogue: /H, rope (sin table == cos table), write bf16
  const int ccol = lane & 15, crow = (lane >> 4) * 4;
#pragma unroll
  for (int n = 0; n < 2; ++n) {
    const int col = n * 16 + ccol;
    const int i = col >> 1;
    const float freq = powf(10000.0f, -(float)i / 16.0f);
#pragma unroll
    for (int r = 0; r < 4; ++r) {
      const int row = m0 + wave * 16 + crow + r;
      float v = acc[n][r] * (1.0f / 16.0f);
      float other = __shfl_xor(v, 1, 64);
      float c = cosf((float)(row & (S_ - 1)) * freq);
      float outv = (col & 1) ? (other + v) * c : (v - other) * c;
      krb[(size_t)row * 32 + col] = f2bf(outv);
    }
  }
}

// ---------------------------------------------------------------------------
// MFMA flash attention, bf16 inputs, f32 softmax/accum.
// Block: 256 thr = 4 waves; q-tile 64 rows (wave w owns rows w*16..w*16+16);
// k-tiles of 64. Diagonal pairing: block p does q-tiles {p, 31-p} (33 iters).
// ---------------------------------------------------------------------------
#define QK_STRIDE 104   // 96 data + pad; 208B row
#define PV_STRIDE 72    // 64 data + pad; 144B row

__global__ __launch_bounds__(256) void attn_mfma(
    const unsigned short* __restrict__ qnb,  // [4096][1024]
    const unsigned short* __restrict__ qrb,  // [4096][512]
    const unsigned short* __restrict__ knb,  // [4096][1024]
    const unsigned short* __restrict__ krb,  // [4096][32]
    const unsigned short* __restrict__ vvT,  // [1024][4096]: [h*64+d][b*2048+s]
    unsigned short* __restrict__ aob) {      // [4096][1024]
  __shared__ unsigned short Qs[64 * QK_STRIDE];
  __shared__ unsigned short Ks[64 * QK_STRIDE];
  __shared__ unsigned short Vt[64 * PV_STRIDE];
  __shared__ unsigned short Ps[64 * PV_STRIDE];
  const int tid = threadIdx.x;
  const int lane = tid & 63;
  const int wave = tid >> 6;
  const int bh = blockIdx.y;
  const int b = bh >> 4, h = bh & 15;
  const size_t rowbase = (size_t)b * S_;
  const int frow = lane & 15, fg = lane >> 4;
  const int ccol = lane & 15, crow = (lane >> 4) * 4;
  const float C2 = 0.10206207261596575f * 1.4426950408889634f;  // scale*log2(e)

  for (int half = 0; half < 2; ++half) {
    const int q0 = (half ? (31 - blockIdx.x) : blockIdx.x) * 64;
    __syncthreads();  // previous half's Qs reads complete
    {  // load Q tile: nope 64 + rope 32 bf16 per row
      int g = tid;
#pragma unroll
      for (int rep = 0; rep < 2; ++rep, g += 256) {
        int row = g >> 3, col = (g & 7) * 8;
        *(uint4*)&Qs[row * QK_STRIDE + col] =
            *(const uint4*)&qnb[(size_t)(rowbase + q0 + row) * 1024 + (h << 6) + col];
      }
      int row = tid >> 2, col = (tid & 3) * 8;
      *(uint4*)&Qs[row * QK_STRIDE + 64 + col] =
          *(const uint4*)&qrb[(size_t)(rowbase + q0 + row) * 512 + (h << 5) + col];
    }

    float m[4] = {-1e30f, -1e30f, -1e30f, -1e30f};
    float l[4] = {0.f, 0.f, 0.f, 0.f};
    f32x4 acc_o[4];
#pragma unroll
    for (int n = 0; n < 4; ++n) acc_o[n] = (f32x4){0.f, 0.f, 0.f, 0.f};

    for (int k0 = 0; k0 <= q0; k0 += 64) {
      __syncthreads();
      {  // load K tile + Vt tile
        int g = tid;
#pragma unroll
        for (int rep = 0; rep < 2; ++rep, g += 256) {
          int row = g >> 3, col = (g & 7) * 8;
          *(uint4*)&Ks[row * QK_STRIDE + col] =
              *(const uint4*)&knb[(size_t)(rowbase + k0 + row) * 1024 + (h << 6) + col];
          *(uint4*)&Vt[row * PV_STRIDE + col] =
              *(const uint4*)&vvT[(size_t)((h << 6) + row) * 4096 + b * S_ + k0 + col];
        }
        int row = tid >> 2, col = (tid & 3) * 8;
        *(uint4*)&Ks[row * QK_STRIDE + 64 + col] =
            *(const uint4*)&krb[(size_t)(rowbase + k0 + row) * 32 + col];
      }
      __syncthreads();

      // ---- QK^T ----
      f32x4 sa[4];
#pragma unroll
      for (int n = 0; n < 4; ++n) sa[n] = (f32x4){0.f, 0.f, 0.f, 0.f};
#pragma unroll
      for (int c = 0; c < 3; ++c) {
        short8 aq = *(const short8*)&Qs[(wave * 16 + frow) * QK_STRIDE + c * 32 + fg * 8];
#pragma unroll
        for (int n = 0; n < 4; ++n) {
          short8 bk = *(const short8*)&Ks[(n * 16 + frow) * QK_STRIDE + c * 32 + fg * 8];
          sa[n] = __builtin_amdgcn_mfma_f32_16x16x32_bf16(aq, bk, sa[n], 0, 0, 0);
        }
      }
      if (k0 == q0) {  // diagonal tile: mask k > q
#pragma unroll
        for (int n = 0; n < 4; ++n) {
          int kg = n * 16 + ccol;
#pragma unroll
          for (int r = 0; r < 4; ++r)
            if (kg > wave * 16 + crow + r) sa[n][r] = -1e30f;
        }
      }
      // ---- online softmax ----
      float mx[4];
#pragma unroll
      for (int r = 0; r < 4; ++r) {
        mx[r] = fmaxf(fmaxf(sa[0][r], sa[1][r]), fmaxf(sa[2][r], sa[3][r]));
#pragma unroll
        for (int off = 1; off <= 8; off <<= 1)
          mx[r] = fmaxf(mx[r], __shfl_xor(mx[r], off, 64));
      }
      int nogrow = (mx[0] <= m[0]) & (mx[1] <= m[1]) & (mx[2] <= m[2]) & (mx[3] <= m[3]);
      if (!__all(nogrow)) {
#pragma unroll
        for (int r = 0; r < 4; ++r) {
          float mn = fmaxf(m[r], mx[r]);
          float ra = exp2f((m[r] - mn) * C2);
          m[r] = mn;
          l[r] *= ra;
#pragma unroll
          for (int n = 0; n < 4; ++n) acc_o[n][r] *= ra;
        }
      }
      float p[4][4];
#pragma unroll
      for (int r = 0; r < 4; ++r) {
        float rs = 0.f;
#pragma unroll
        for (int n = 0; n < 4; ++n) {
          p[n][r] = exp2f((sa[n][r] - m[r]) * C2);
          rs += p[n][r];
        }
#pragma unroll
        for (int off = 1; off <= 8; off <<= 1) rs += __shfl_xor(rs, off, 64);
        l[r] += rs;
      }
      // ---- P -> LDS (wave-private rows), then PV ----
#pragma unroll
      for (int n = 0; n < 4; ++n)
#pragma unroll
        for (int r = 0; r < 4; ++r)
          Ps[(wave * 16 + crow + r) * PV_STRIDE + n * 16 + ccol] = f2bf(p[n][r]);
      __builtin_amdgcn_wave_barrier();
#pragma unroll
      for (int c = 0; c < 2; ++c) {
        short8 ap = *(const short8*)&Ps[(wave * 16 + frow) * PV_STRIDE + c * 32 + fg * 8];
#pragma unroll
        for (int n = 0; n < 4; ++n) {
          short8 bv = *(const short8*)&Vt[(n * 16 + frow) * PV_STRIDE + c * 32 + fg * 8];
          acc_o[n] = __builtin_amdgcn_mfma_f32_16x16x32_bf16(ap, bv, acc_o[n], 0, 0, 0);
        }
      }
      __builtin_amdgcn_wave_barrier();
    }
    // ---- epilogue ----
    float inv[4];
#pragma unroll
    for (int r = 0; r < 4; ++r) inv[r] = 1.f / l[r];
#pragma unroll
    for (int n = 0; n < 4; ++n)
#pragma unroll
      for (int r = 0; r < 4; ++r)
        aob[(size_t)(rowbase + q0 + wave * 16 + crow + r) * 1024 + (h << 6) + n * 16 + ccol] =
            f2bf(acc_o[n][r] * inv[r]);
  }
}

// ---------------------------------------------------------------------------
extern "C" void kernel_launch(void* const* d_in, const int* in_sizes, int n_in,
                              void* d_out, int out_size, void* d_ws, size_t ws_size,
                              hipStream_t stream) {
  const float* x        = (const float*)d_in[0];
  const float* w_cq     = (const float*)d_in[1];
  const float* w_q_nope = (const float*)d_in[2];
  const float* w_q_rope = (const float*)d_in[3];
  const float* q_g      = (const float*)d_in[4];
  const float* w_ckv    = (const float*)d_in[5];
  const float* w_k_nope = (const float*)d_in[6];
  const float* w_v      = (const float*)d_in[7];
  const float* kv_g     = (const float*)d_in[8];
  const float* w_k_rope = (const float*)d_in[9];
  const float* w_proj   = (const float*)d_in[10];
  float* out = (float*)d_out;

  // ---- workspace layout (bf16) ----
  char* w = (char*)d_ws;
  unsigned short* xb    = (unsigned short*)w; w += (size_t)ROWS * 2048 * 2;
  unsigned short* cqb   = (unsigned short*)w; w += (size_t)ROWS * QRANK * 2;
  unsigned short* ckvb  = (unsigned short*)w; w += (size_t)ROWS * KVRANK * 2;
  unsigned short* qnb   = (unsigned short*)w; w += (size_t)ROWS * 1024 * 2;
  unsigned short* qrb   = (unsigned short*)w; w += (size_t)ROWS * 512 * 2;
  unsigned short* knb   = (unsigned short*)w; w += (size_t)ROWS * 1024 * 2;
  unsigned short* vvb   = (unsigned short*)w; w += (size_t)ROWS * 1024 * 2;
  unsigned short* vvT   = (unsigned short*)w; w += (size_t)1024 * ROWS * 2;
  unsigned short* krb   = (unsigned short*)w; w += (size_t)ROWS * 32 * 2;
  unsigned short* aob   = (unsigned short*)w; w += (size_t)ROWS * 1024 * 2;
  unsigned short* wcqT  = (unsigned short*)w; w += (size_t)QRANK * 2048 * 2;
  unsigned short* wqnT  = (unsigned short*)w; w += (size_t)1024 * QRANK * 2;
  unsigned short* wqrT  = (unsigned short*)w; w += (size_t)512 * QRANK * 2;
  unsigned short* wckvT = (unsigned short*)w; w += (size_t)KVRANK * 2048 * 2;
  unsigned short* wknT  = (unsigned short*)w; w += (size_t)1024 * KVRANK * 2;
  unsigned short* wvT   = (unsigned short*)w; w += (size_t)1024 * KVRANK * 2;
  unsigned short* wprojT= (unsigned short*)w; w += (size_t)2048 * 1024 * 2;
  unsigned short* wkrT  = (unsigned short*)w; w += (size_t)32 * 2048 * 2;

  // ---- casts & weight transposes ----
  cast_to_bf16<<<ROWS * 2048 / (256 * 8), 256, 0, stream>>>(x, xb, ROWS * 2048);
  transpose_cast<<<dim3(QRANK / 32, 2048 / 32), 256, 0, stream>>>(w_cq, wcqT, 2048, QRANK);
  transpose_cast<<<dim3(1024 / 32, QRANK / 32), 256, 0, stream>>>(w_q_nope, wqnT, QRANK, 1024);
  transpose_cast<<<dim3(512 / 32, QRANK / 32), 256, 0, stream>>>(w_q_rope, wqrT, QRANK, 512);
  transpose_cast<<<dim3(KVRANK / 32, 2048 / 32), 256, 0, stream>>>(w_ckv, wckvT, 2048, KVRANK);
  transpose_cast<<<dim3(1024 / 32, KVRANK / 32), 256, 0, stream>>>(w_k_nope, wknT, KVRANK, 1024);
  transpose_cast<<<dim3(1024 / 32, KVRANK / 32), 256, 0, stream>>>(w_v, wvT, KVRANK, 1024);
  transpose_cast<<<dim3(2048 / 32, 1024 / 32), 256, 0, stream>>>(w_proj, wprojT, 1024, 2048);
  transpose_cast<<<dim3(32 / 32, 2048 / 32), 256, 0, stream>>>(w_k_rope, wkrT, 2048, 32);

  // ---- projections (bf16 MFMA, bf16 outputs) ----
  gemm_bf16<<<dim3(QRANK / 128, ROWS / 128), 256, 0, stream>>>(xb, wcqT, cqb, ROWS, QRANK, 2048, 1);
  rmsnorm_bf16<<<ROWS, 256, 0, stream>>>(cqb, q_g, QRANK, 1.0f / QRANK);
  gemm_bf16<<<dim3(1024 / 128, ROWS / 128), 256, 0, stream>>>(cqb, wqnT, qnb, ROWS, 1024, QRANK, 1);
  gemm_bf16<<<dim3(512 / 128, ROWS / 128), 256, 0, stream>>>(cqb, wqrT, qrb, ROWS, 512, QRANK, 1);
  rope_q_bf16<<<ROWS, 256, 0, stream>>>(qrb);
  gemm_bf16<<<dim3(KVRANK / 128, ROWS / 128), 256, 0, stream>>>(xb, wckvT, ckvb, ROWS, KVRANK, 2048, 1);
  rmsnorm_bf16<<<ROWS, 256, 0, stream>>>(ckvb, kv_g, KVRANK, 1.0f / KVRANK);
  gemm_bf16<<<dim3(1024 / 128, ROWS / 128), 256, 0, stream>>>(ckvb, wknT, knb, ROWS, 1024, KVRANK, 1);
  gemm_bf16<<<dim3(1024 / 128, ROWS / 128), 256, 0, stream>>>(ckvb, wvT, vvb, ROWS, 1024, KVRANK, 1);
  transpose_bf16<<<dim3(1024 / 32, ROWS / 32), 256, 0, stream>>>(vvb, vvT, ROWS, 1024);
  // k_rope via MFMA GEMM with fused rope epilogue
  gemm_kr_rope<<<ROWS / 64, 256, 0, stream>>>(xb, wkrT, krb);

  // ---- attention (MFMA flash) ----
  attn_mfma<<<dim3(16, 32), 256, 0, stream>>>(qnb, qrb, knb, krb, vvT, aob);

  // ---- output projection ----
  gemm_bf16<<<dim3(2048 / 128, ROWS / 128), 256, 0, stream>>>(aob, wprojT, out, ROWS, 2048, 1024, 0);
}